// Round 4
// baseline (347.803 us; speedup 1.0000x reference)
//
#include <hip/hip_runtime.h>
#include <stdint.h>

// ---------------------------------------------------------------------------
// Fully fused wavelet window-attention (f16 edition).
//   x: (8,64,256,256) f32; w_qkv_lh: (192,64); w_qkv_m: (384,128)
//   Block = 256 thr (4 waves): one (unit, quarter) = 4 orig rows x 64 cols.
//   bands[4][px64][c64] f16 (32KB, 16B-granule XOR swz), reused as
//     y[slot][ych64][px64] (ych = head-deinterleaved channel).
//   qk f16 48KB: (tl,wl,q) at u16 idx G*256 + (n>>1)*128 + ((wl^(G&7))<<3)
//     + (n&1)*4 + q, where G=tl>>2, n=tl&3, q = s index (r0c0,r0c1,r1c0,r1c1).
//   Conv = MFMA 16x16x32 f16; attention dots = v_dot2_f32_f16 (packed).
// ---------------------------------------------------------------------------

typedef _Float16 halfT;
typedef __attribute__((ext_vector_type(2))) _Float16 half2T;
typedef __attribute__((ext_vector_type(8))) _Float16 half8;
typedef __attribute__((ext_vector_type(4))) float f32x4;

union H8 { half8 v; half2T h2[4]; uint32_t u[4]; };
union H2U { half2T h; uint32_t u; };

static __device__ __forceinline__ uint16_t f2h(float f){
  union { halfT h; uint16_t u; } x; x.h = (halfT)f; return x.u;
}
static __device__ __forceinline__ float h2f(uint16_t u){
  union { uint16_t u; halfT h; } x; x.u = u; return (float)x.h;
}
static __device__ __forceinline__ float dot4(half2T a0, half2T a1,
                                             half2T b0, half2T b1){
#if __has_builtin(__builtin_amdgcn_fdot2)
  return __builtin_amdgcn_fdot2(a1, b1, __builtin_amdgcn_fdot2(a0, b0, 0.f, false), false);
#else
  half2T p = a0*b0 + a1*b1;
  return (float)p.x + (float)p.y;
#endif
}
static __device__ __forceinline__ half2T h2shfl_xor(half2T v, int m){
  H2U a; a.h = v; a.u = __shfl_xor(a.u, m); return a.h;
}
static __device__ __forceinline__ half2T pk2(float e){
#if __has_builtin(__builtin_amdgcn_cvt_pkrtz)
  union { __fp16 __attribute__((ext_vector_type(2))) p; half2T h; } c;
  c.p = __builtin_amdgcn_cvt_pkrtz(e, e);
  return c.h;
#else
  half2T r; r.x = (halfT)e; r.y = (halfT)e; return r;
#endif
}

// -------------------- weight cast f32 -> f16 (layout kept [t][c]) -----------
__global__ void k_wt(const float* __restrict__ wlh, const float* __restrict__ wm,
                     halfT* __restrict__ wH){
  int i = blockIdx.x * 256 + threadIdx.x;
  if (i < 12288)      wH[i] = (halfT)wlh[i];
  else if (i < 61440) wH[i] = (halfT)wm[i - 12288];
}

// read one 16B granule: quads for heads {2*npair, 2*npair+1} of channel-group G
static __device__ __forceinline__ half8 rdq(const uint16_t* qk, int G, int npair, int wl){
  return *(const half8*)&qk[G*256 + npair*128 + ((wl ^ (G & 7)) << 3)];
}

template<int KS>   // KS = K/32; CH = 32*KS; T = 3*CH
static __device__ __forceinline__ void conv_path(const halfT* __restrict__ w,
    const uint16_t* __restrict__ bands, uint16_t* __restrict__ qk,
    int lane, int wv, int bbase){
  const int CH = KS * 32;
  const int nM = 6 * KS;
  const int mrow = lane & 15, g = lane >> 4;
  const int pxb  = wv * 16 + mrow;
  const int wl = (pxb & 31) >> 1, q = (pxb >> 5)*2 + (pxb & 1);
  half8 bfr[KS];
  #pragma unroll
  for (int ks = 0; ks < KS; ++ks){
    int band = bbase + (ks >> 1);
    int c0   = (ks & 1) * 32 + g * 8;
    bfr[ks] = *(const half8*)&bands[band*4096 + pxb*64 + (c0 ^ ((pxb & 7) << 3))];
  }
  for (int mt = 0; mt < nM; ++mt){
    f32x4 acc = {0.f, 0.f, 0.f, 0.f};
    #pragma unroll
    for (int ks = 0; ks < KS; ++ks){
      half8 a = *(const half8*)&w[(size_t)(mt*16 + mrow)*CH + ks*32 + g*8];
      acc = __builtin_amdgcn_mfma_f32_16x16x32_f16(a, bfr[ks], acc, 0, 0, 0);
    }
    #pragma unroll
    for (int r = 0; r < 4; ++r){
      int tl = mt*16 + g*4 + r;
      int G  = tl >> 2;
      int idx = G*256 + (tl & 2)*64 + ((wl ^ (G & 7)) << 3) + (tl & 1)*4 + q;
      qk[idx] = f2h(acc[r]);
    }
  }
}

__global__ __launch_bounds__(256, 2) void k_fused(const float* __restrict__ x,
    const halfT* __restrict__ wH, float* __restrict__ out){
  __shared__ __align__(16) uint16_t bands[4 * 4096];  // 32 KB
  __shared__ __align__(16) uint16_t qk[96 * 256];     // 48 KB

  const int tid  = threadIdx.x;
  const int wv   = tid >> 6, lane = tid & 63;
  const int unit = blockIdx.x >> 2, q4 = blockIdx.x & 3;
  const int b = unit >> 6, hw = unit & 63;
  const int col0 = q4 * 64;
  const float* xb = x + (size_t)b * 64 * 65536;

  // ---------------- phase A: load x + Haar DWT -> bands -------------------
  for (int it = 0; it < 8; ++it){
    int idx = it * 256 + tid;
    int j = idx & 15, rp = (idx >> 4) & 1, c = idx >> 5;
    const float* src = xb + (size_t)c * 65536 + (size_t)(4*hw + 2*rp) * 256 + col0 + 4*j;
    float4 r0 = *(const float4*)src;
    float4 r1 = *(const float4*)(src + 256);
    float v[2][4];
    v[0][0] = 0.5f*( r0.x + r0.y + r1.x + r1.y);
    v[0][1] = 0.5f*(-r0.x - r0.y + r1.x + r1.y);
    v[0][2] = 0.5f*(-r0.x + r0.y - r1.x + r1.y);
    v[0][3] = 0.5f*( r0.x - r0.y - r1.x + r1.y);
    v[1][0] = 0.5f*( r0.z + r0.w + r1.z + r1.w);
    v[1][1] = 0.5f*(-r0.z - r0.w + r1.z + r1.w);
    v[1][2] = 0.5f*(-r0.z + r0.w - r1.z + r1.w);
    v[1][3] = 0.5f*( r0.z - r0.w - r1.z + r1.w);
    #pragma unroll
    for (int e = 0; e < 2; ++e){
      int px = rp*32 + 2*j + e;
      int off = c ^ ((px & 7) << 3);
      #pragma unroll
      for (int bb = 0; bb < 4; ++bb)
        bands[bb*4096 + px*64 + off] = f2h(v[e][bb]);
    }
  }
  __syncthreads();

  // ---------------- phases B/C: per path conv (MFMA) + attention ----------
  for (int path = 0; path < 3; ++path){
    if (path == 1) conv_path<4>(wH + 12288, bands, qk, lane, wv, 1);
    else           conv_path<2>(wH,         bands, qk, lane, wv, (path == 0) ? 0 : 3);
    __syncthreads();

    const float scale = (path == 1) ? 0.17677669529663687f : 0.25f;
    const halfT sh = (halfT)scale;
    const half8 s8 = { sh, sh, sh, sh, sh, sh, sh, sh };

    if (path != 1){
      // low/high: heads n=0..3, c=16/head. lane = (ci 0..15, dg 0..3); d=dg*4+dd
      const int yslot = (path == 0) ? 0 : 3;
      const int ci = lane >> 2, dg = lane & 3;
      for (int wi = 0; wi < 4; ++wi){
        const int wl = wv*4 + wi;
        H8 qa, qb;
        qa.v = rdq(qk, ci, 0, wl) * s8;
        qb.v = rdq(qk, ci, 1, wl) * s8;
        float av[4][4];
        #pragma unroll
        for (int dd = 0; dd < 4; ++dd){
          int Gk = 16 + dg*4 + dd;
          H8 ka, kb; ka.v = rdq(qk, Gk, 0, wl); kb.v = rdq(qk, Gk, 1, wl);
          av[0][dd] = dot4(qa.h2[0], qa.h2[1], ka.h2[0], ka.h2[1]);
          av[1][dd] = dot4(qa.h2[2], qa.h2[3], ka.h2[2], ka.h2[3]);
          av[2][dd] = dot4(qb.h2[0], qb.h2[1], kb.h2[0], kb.h2[1]);
          av[3][dd] = dot4(qb.h2[2], qb.h2[3], kb.h2[2], kb.h2[3]);
        }
        float sm[4];
        #pragma unroll
        for (int n = 0; n < 4; ++n){
          float m = fmaxf(fmaxf(av[n][0], av[n][1]), fmaxf(av[n][2], av[n][3]));
          m = fmaxf(m, __shfl_xor(m, 1));
          m = fmaxf(m, __shfl_xor(m, 2));
          float s = 0.f;
          #pragma unroll
          for (int dd = 0; dd < 4; ++dd){ av[n][dd] = __expf(av[n][dd] - m); s += av[n][dd]; }
          s += __shfl_xor(s, 1);
          s += __shfl_xor(s, 2);
          sm[n] = s;
        }
        half2T po[4][2];
        #pragma unroll
        for (int n = 0; n < 4; ++n){ po[n][0] = (half2T)0; po[n][1] = (half2T)0; }
        #pragma unroll
        for (int dd = 0; dd < 4; ++dd){
          int Gv = 32 + dg*4 + dd;
          H8 va, vb; va.v = rdq(qk, Gv, 0, wl); vb.v = rdq(qk, Gv, 1, wl);
          half2T p0 = pk2(av[0][dd]), p1 = pk2(av[1][dd]);
          half2T p2 = pk2(av[2][dd]), p3 = pk2(av[3][dd]);
          po[0][0] += p0*va.h2[0]; po[0][1] += p0*va.h2[1];
          po[1][0] += p1*va.h2[2]; po[1][1] += p1*va.h2[3];
          po[2][0] += p2*vb.h2[0]; po[2][1] += p2*vb.h2[1];
          po[3][0] += p3*vb.h2[2]; po[3][1] += p3*vb.h2[3];
        }
        #pragma unroll
        for (int n = 0; n < 4; ++n){
          #pragma unroll
          for (int k = 0; k < 2; ++k){
            po[n][k] += h2shfl_xor(po[n][k], 1);
            po[n][k] += h2shfl_xor(po[n][k], 2);
          }
          float inv = __builtin_amdgcn_rcpf(sm[n]);
          halfT ih = (halfT)inv;
          half2T iv = { ih, ih };
          half2T r0 = po[n][0] * iv, r1 = po[n][1] * iv;
          halfT val = (dg & 2) ? ((dg & 1) ? r1.y : r1.x)
                               : ((dg & 1) ? r0.y : r0.x);
          int px  = (dg >> 1)*32 + 2*wl + (dg & 1);
          int ych = ci | (n << 4);
          union { halfT h; uint16_t u; } cv; cv.h = val;
          bands[yslot*4096 + ych*64 + (px ^ ((ych & 7) << 3))] = cv.u;
        }
      }
    } else {
      // mid: heads n=0..3, c=32/head. lane = (ci 0..31, dg 0..1); d=dg*16+dd
      const int ci = lane >> 1, dg = lane & 1;
      for (int wi = 0; wi < 4; ++wi){
        const int wl = wv*4 + wi;
        #pragma unroll
        for (int npair = 0; npair < 2; ++npair){
          H8 qv; qv.v = rdq(qk, ci, npair, wl) * s8;
          float av[2][16];
          #pragma unroll
          for (int dd = 0; dd < 16; ++dd){
            int Gk = 32 + dg*16 + dd;
            H8 kv; kv.v = rdq(qk, Gk, npair, wl);
            av[0][dd] = dot4(qv.h2[0], qv.h2[1], kv.h2[0], kv.h2[1]);
            av[1][dd] = dot4(qv.h2[2], qv.h2[3], kv.h2[2], kv.h2[3]);
          }
          float sm[2];
          #pragma unroll
          for (int n2 = 0; n2 < 2; ++n2){
            float m0 = av[n2][0];
            #pragma unroll
            for (int dd = 1; dd < 16; ++dd) m0 = fmaxf(m0, av[n2][dd]);
            m0 = fmaxf(m0, __shfl_xor(m0, 1));
            float s = 0.f;
            #pragma unroll
            for (int dd = 0; dd < 16; ++dd){ av[n2][dd] = __expf(av[n2][dd] - m0); s += av[n2][dd]; }
            s += __shfl_xor(s, 1);
            sm[n2] = s;
          }
          half2T po[2][2];
          po[0][0] = (half2T)0; po[0][1] = (half2T)0;
          po[1][0] = (half2T)0; po[1][1] = (half2T)0;
          #pragma unroll
          for (int dd = 0; dd < 16; ++dd){
            int Gv = 64 + dg*16 + dd;
            H8 vv; vv.v = rdq(qk, Gv, npair, wl);
            half2T p0 = pk2(av[0][dd]), p1 = pk2(av[1][dd]);
            po[0][0] += p0*vv.h2[0]; po[0][1] += p0*vv.h2[1];
            po[1][0] += p1*vv.h2[2]; po[1][1] += p1*vv.h2[3];
          }
          #pragma unroll
          for (int n2 = 0; n2 < 2; ++n2){
            po[n2][0] += h2shfl_xor(po[n2][0], 1);
            po[n2][1] += h2shfl_xor(po[n2][1], 1);
            float inv = __builtin_amdgcn_rcpf(sm[n2]);
            halfT ih = (halfT)inv;
            half2T iv = { ih, ih };
            // lane dg writes s-pair dg of its quad as one u32
            H2U wd; wd.h = po[n2][dg] * iv;
            int n   = npair*2 + n2;
            int slot = 1 + (ci >> 4);
            int ych  = (ci & 15) | (n << 4);
            int px0  = dg*32 + 2*wl;
            int u16i = slot*4096 + ych*64 + (px0 ^ ((ych & 7) << 3));
            *(uint32_t*)&bands[u16i] = wd.u;
          }
        }
      }
    }
    __syncthreads();
  }

  // ---------------- phase D: iDWT + coalesced store -----------------------
  for (int it = 0; it < 4; ++it){
    int s = it * 256 + tid;
    int ch = s >> 4, row = (s >> 2) & 3, seg = s & 3;
    int ych = (ch >> 2) | ((ch & 3) << 4);
    int px0 = (row >> 1)*32 + seg*8;
    int base = ych*64 + (px0 ^ ((ych & 7) << 3));
    H8 y0, y1, y2, y3;
    y0.v = *(const half8*)&bands[0*4096 + base];
    y1.v = *(const half8*)&bands[1*4096 + base];
    y2.v = *(const half8*)&bands[2*4096 + base];
    y3.v = *(const half8*)&bands[3*4096 + base];
    float o[16];
    #pragma unroll
    for (int p = 0; p < 8; ++p){
      float a0 = (float)y0.v[p];
      float a1 = (float)y1.v[p];
      float a2 = (float)y2.v[p];
      float a3 = (float)y3.v[p];
      float e0, e1;
      if (row & 1){ e0 = 0.5f*(a0 + a1 - a2 - a3); e1 = 0.5f*(a0 + a1 + a2 + a3); }
      else        { e0 = 0.5f*(a0 - a1 - a2 + a3); e1 = 0.5f*(a0 - a1 + a2 - a3); }
      o[2*p] = e0; o[2*p + 1] = e1;
    }
    float* dst = out + (((size_t)b*64 + ch)*256 + (size_t)(4*hw + row))*256 + col0 + seg*16;
    ((float4*)dst)[0] = make_float4(o[0],  o[1],  o[2],  o[3]);
    ((float4*)dst)[1] = make_float4(o[4],  o[5],  o[6],  o[7]);
    ((float4*)dst)[2] = make_float4(o[8],  o[9],  o[10], o[11]);
    ((float4*)dst)[3] = make_float4(o[12], o[13], o[14], o[15]);
  }
}

// ---------------------------------------------------------------------------
extern "C" void kernel_launch(void* const* d_in, const int* in_sizes, int n_in,
                              void* d_out, int out_size, void* d_ws, size_t ws_size,
                              hipStream_t stream){
  const float* x   = (const float*)d_in[0];
  const float* wlh = (const float*)d_in[1];
  const float* wm  = (const float*)d_in[2];
  float* out = (float*)d_out;
  halfT* wH = (halfT*)d_ws;                // 61440 f16 = 122880 B

  hipLaunchKernelGGL(k_wt,    dim3(240),  dim3(256), 0, stream, wlh, wm, wH);
  hipLaunchKernelGGL(k_fused, dim3(2048), dim3(256), 0, stream, x, wH, out);
}

// Round 5
// 239.879 us; speedup vs baseline: 1.4499x; 1.4499x over previous
//
#include <hip/hip_runtime.h>
#include <stdint.h>

// ---------------------------------------------------------------------------
// Fully fused wavelet window-attention (f16, 8-wave blocks).
//   x: (8,64,256,256) f32; w_qkv_lh: (192,64); w_qkv_m: (384,128)
//   Block = 512 thr (8 waves): one (unit, quarter) = 4 orig rows x 64 cols.
//   bands[4][px64][c64] f16 (32KB, 16B-granule XOR swz), reused as
//     y[slot][ych64][px64] (ych = head-deinterleaved channel).
//   qk f16 48KB: (tl,wl,q) at u16 idx G*256 + (n>>1)*128 + ((wl^(G&7))<<3)
//     + (n&1)*4 + q, where G=tl>>2, n=tl&3, q = s index (r0c0,r0c1,r1c0,r1c1).
//   Conv: MFMA 16x16x32 f16, waves = (N-tile 0..3) x (M-half 0..1).
// ---------------------------------------------------------------------------

typedef _Float16 halfT;
typedef __attribute__((ext_vector_type(2))) _Float16 half2T;
typedef __attribute__((ext_vector_type(8))) _Float16 half8;
typedef __attribute__((ext_vector_type(4))) float f32x4;

union H8 { half8 v; half2T h2[4]; uint32_t u[4]; };
union H2U { half2T h; uint32_t u; };

static __device__ __forceinline__ uint16_t f2h(float f){
  union { halfT h; uint16_t u; } x; x.h = (halfT)f; return x.u;
}
static __device__ __forceinline__ float dot4(half2T a0, half2T a1,
                                             half2T b0, half2T b1){
#if __has_builtin(__builtin_amdgcn_fdot2)
  return __builtin_amdgcn_fdot2(a1, b1, __builtin_amdgcn_fdot2(a0, b0, 0.f, false), false);
#else
  half2T p = a0*b0 + a1*b1;
  return (float)p.x + (float)p.y;
#endif
}
static __device__ __forceinline__ half2T h2shfl_xor(half2T v, int m){
  H2U a; a.h = v; a.u = __shfl_xor(a.u, m); return a.h;
}
static __device__ __forceinline__ half2T pk2(float e){
#if __has_builtin(__builtin_amdgcn_cvt_pkrtz)
  union { __fp16 __attribute__((ext_vector_type(2))) p; half2T h; } c;
  c.p = __builtin_amdgcn_cvt_pkrtz(e, e);
  return c.h;
#else
  half2T r; r.x = (halfT)e; r.y = (halfT)e; return r;
#endif
}

// -------------------- weight cast f32 -> f16 (layout kept [t][c]) -----------
__global__ void k_wt(const float* __restrict__ wlh, const float* __restrict__ wm,
                     halfT* __restrict__ wH){
  int i = blockIdx.x * 256 + threadIdx.x;
  if (i < 12288)      wH[i] = (halfT)wlh[i];
  else if (i < 61440) wH[i] = (halfT)wm[i - 12288];
}

// read one 16B granule: quads for heads {2*npair, 2*npair+1} of channel-group G
static __device__ __forceinline__ half8 rdq(const uint16_t* qk, int G, int npair, int wl){
  return *(const half8*)&qk[G*256 + npair*128 + ((wl ^ (G & 7)) << 3)];
}

template<int KS>   // KS = K/32; CH = 32*KS; T = 3*CH
static __device__ __forceinline__ void conv_path(const halfT* __restrict__ w,
    const uint16_t* __restrict__ bands, uint16_t* __restrict__ qk,
    int lane, int nt, int mhalf, int bbase){
  const int CH = KS * 32;
  const int nM2 = 3 * KS;                   // half of the M-tiles
  const int mrow = lane & 15, g = lane >> 4;
  const int pxb  = nt * 16 + mrow;
  const int wl = (pxb & 31) >> 1, q = (pxb >> 5)*2 + (pxb & 1);
  half8 bfr[KS];
  #pragma unroll
  for (int ks = 0; ks < KS; ++ks){
    int band = bbase + (ks >> 1);
    int c0   = (ks & 1) * 32 + g * 8;
    bfr[ks] = *(const half8*)&bands[band*4096 + pxb*64 + (c0 ^ ((pxb & 7) << 3))];
  }
  for (int mi = 0; mi < nM2; ++mi){
    int mt = mhalf * nM2 + mi;
    f32x4 acc = {0.f, 0.f, 0.f, 0.f};
    #pragma unroll
    for (int ks = 0; ks < KS; ++ks){
      half8 a = *(const half8*)&w[(size_t)(mt*16 + mrow)*CH + ks*32 + g*8];
      acc = __builtin_amdgcn_mfma_f32_16x16x32_f16(a, bfr[ks], acc, 0, 0, 0);
    }
    #pragma unroll
    for (int r = 0; r < 4; ++r){
      int tl = mt*16 + g*4 + r;
      int G  = tl >> 2;
      int idx = G*256 + (tl & 2)*64 + ((wl ^ (G & 7)) << 3) + (tl & 1)*4 + q;
      qk[idx] = f2h(acc[r]);
    }
  }
}

__global__ __launch_bounds__(512, 4) void k_fused(const float* __restrict__ x,
    const halfT* __restrict__ wH, float* __restrict__ out){
  __shared__ __align__(16) uint16_t bands[4 * 4096];  // 32 KB
  __shared__ __align__(16) uint16_t qk[96 * 256];     // 48 KB

  const int tid  = threadIdx.x;
  const int wv   = tid >> 6, lane = tid & 63;
  const int unit = blockIdx.x >> 2, q4 = blockIdx.x & 3;
  const int b = unit >> 6, hw = unit & 63;
  const int col0 = q4 * 64;
  const float* xb = x + (size_t)b * 64 * 65536;

  // ---------------- phase A: load x + Haar DWT -> bands -------------------
  for (int it = 0; it < 4; ++it){
    int idx = it * 512 + tid;
    int j = idx & 15, rp = (idx >> 4) & 1, c = idx >> 5;
    const float* src = xb + (size_t)c * 65536 + (size_t)(4*hw + 2*rp) * 256 + col0 + 4*j;
    float4 r0 = *(const float4*)src;
    float4 r1 = *(const float4*)(src + 256);
    float v[2][4];
    v[0][0] = 0.5f*( r0.x + r0.y + r1.x + r1.y);
    v[0][1] = 0.5f*(-r0.x - r0.y + r1.x + r1.y);
    v[0][2] = 0.5f*(-r0.x + r0.y - r1.x + r1.y);
    v[0][3] = 0.5f*( r0.x - r0.y - r1.x + r1.y);
    v[1][0] = 0.5f*( r0.z + r0.w + r1.z + r1.w);
    v[1][1] = 0.5f*(-r0.z - r0.w + r1.z + r1.w);
    v[1][2] = 0.5f*(-r0.z + r0.w - r1.z + r1.w);
    v[1][3] = 0.5f*( r0.z - r0.w - r1.z + r1.w);
    #pragma unroll
    for (int e = 0; e < 2; ++e){
      int px = rp*32 + 2*j + e;
      int off = c ^ ((px & 7) << 3);
      #pragma unroll
      for (int bb = 0; bb < 4; ++bb)
        bands[bb*4096 + px*64 + off] = f2h(v[e][bb]);
    }
  }
  __syncthreads();

  // ---------------- phases B/C: per path conv (MFMA) + attention ----------
  const int nt = wv & 3, mhalf = wv >> 2;
  for (int path = 0; path < 3; ++path){
    if (path == 1) conv_path<4>(wH + 12288, bands, qk, lane, nt, mhalf, 1);
    else           conv_path<2>(wH,         bands, qk, lane, nt, mhalf, (path == 0) ? 0 : 3);
    __syncthreads();

    const float scale = (path == 1) ? 0.17677669529663687f : 0.25f;
    const halfT sh = (halfT)scale;
    const half8 s8 = { sh, sh, sh, sh, sh, sh, sh, sh };

    if (path != 1){
      // low/high: heads n=0..3, c=16/head. lane = (ci 0..15, dg 0..3); d=dg*4+dd
      const int yslot = (path == 0) ? 0 : 3;
      const int ci = lane >> 2, dg = lane & 3;
      for (int wi = 0; wi < 2; ++wi){
        const int wl = wv*2 + wi;
        H8 qa, qb;
        qa.v = rdq(qk, ci, 0, wl) * s8;
        qb.v = rdq(qk, ci, 1, wl) * s8;
        float av[4][4];
        #pragma unroll
        for (int dd = 0; dd < 4; ++dd){
          int Gk = 16 + dg*4 + dd;
          H8 ka, kb; ka.v = rdq(qk, Gk, 0, wl); kb.v = rdq(qk, Gk, 1, wl);
          av[0][dd] = dot4(qa.h2[0], qa.h2[1], ka.h2[0], ka.h2[1]);
          av[1][dd] = dot4(qa.h2[2], qa.h2[3], ka.h2[2], ka.h2[3]);
          av[2][dd] = dot4(qb.h2[0], qb.h2[1], kb.h2[0], kb.h2[1]);
          av[3][dd] = dot4(qb.h2[2], qb.h2[3], kb.h2[2], kb.h2[3]);
        }
        float sm[4];
        #pragma unroll
        for (int n = 0; n < 4; ++n){
          float m = fmaxf(fmaxf(av[n][0], av[n][1]), fmaxf(av[n][2], av[n][3]));
          m = fmaxf(m, __shfl_xor(m, 1));
          m = fmaxf(m, __shfl_xor(m, 2));
          float s = 0.f;
          #pragma unroll
          for (int dd = 0; dd < 4; ++dd){ av[n][dd] = __expf(av[n][dd] - m); s += av[n][dd]; }
          s += __shfl_xor(s, 1);
          s += __shfl_xor(s, 2);
          sm[n] = s;
        }
        half2T po[4][2];
        #pragma unroll
        for (int n = 0; n < 4; ++n){ po[n][0] = (half2T)0; po[n][1] = (half2T)0; }
        #pragma unroll
        for (int dd = 0; dd < 4; ++dd){
          int Gv = 32 + dg*4 + dd;
          H8 va, vb; va.v = rdq(qk, Gv, 0, wl); vb.v = rdq(qk, Gv, 1, wl);
          half2T p0 = pk2(av[0][dd]), p1 = pk2(av[1][dd]);
          half2T p2 = pk2(av[2][dd]), p3 = pk2(av[3][dd]);
          po[0][0] += p0*va.h2[0]; po[0][1] += p0*va.h2[1];
          po[1][0] += p1*va.h2[2]; po[1][1] += p1*va.h2[3];
          po[2][0] += p2*vb.h2[0]; po[2][1] += p2*vb.h2[1];
          po[3][0] += p3*vb.h2[2]; po[3][1] += p3*vb.h2[3];
        }
        #pragma unroll
        for (int n = 0; n < 4; ++n){
          #pragma unroll
          for (int k = 0; k < 2; ++k){
            po[n][k] += h2shfl_xor(po[n][k], 1);
            po[n][k] += h2shfl_xor(po[n][k], 2);
          }
          float inv = __builtin_amdgcn_rcpf(sm[n]);
          halfT ih = (halfT)inv;
          half2T iv = { ih, ih };
          half2T r0 = po[n][0] * iv, r1 = po[n][1] * iv;
          halfT val = (dg & 2) ? ((dg & 1) ? r1.y : r1.x)
                               : ((dg & 1) ? r0.y : r0.x);
          int px  = (dg >> 1)*32 + 2*wl + (dg & 1);
          int ych = ci | (n << 4);
          union { halfT h; uint16_t u; } cv; cv.h = val;
          bands[yslot*4096 + ych*64 + (px ^ ((ych & 7) << 3))] = cv.u;
        }
      }
    } else {
      // mid: heads n=0..3, c=32/head. lane = (ci 0..31, dg 0..1); d=dg*16+dd
      const int ci = lane >> 1, dg = lane & 1;
      for (int wi = 0; wi < 2; ++wi){
        const int wl = wv*2 + wi;
        #pragma unroll
        for (int npair = 0; npair < 2; ++npair){
          H8 qv; qv.v = rdq(qk, ci, npair, wl) * s8;
          float av[2][16];
          #pragma unroll
          for (int dd = 0; dd < 16; ++dd){
            int Gk = 32 + dg*16 + dd;
            H8 kv; kv.v = rdq(qk, Gk, npair, wl);
            av[0][dd] = dot4(qv.h2[0], qv.h2[1], kv.h2[0], kv.h2[1]);
            av[1][dd] = dot4(qv.h2[2], qv.h2[3], kv.h2[2], kv.h2[3]);
          }
          float sm[2];
          #pragma unroll
          for (int n2 = 0; n2 < 2; ++n2){
            float m0 = av[n2][0];
            #pragma unroll
            for (int dd = 1; dd < 16; ++dd) m0 = fmaxf(m0, av[n2][dd]);
            m0 = fmaxf(m0, __shfl_xor(m0, 1));
            float s = 0.f;
            #pragma unroll
            for (int dd = 0; dd < 16; ++dd){ av[n2][dd] = __expf(av[n2][dd] - m0); s += av[n2][dd]; }
            s += __shfl_xor(s, 1);
            sm[n2] = s;
          }
          half2T po[2][2];
          po[0][0] = (half2T)0; po[0][1] = (half2T)0;
          po[1][0] = (half2T)0; po[1][1] = (half2T)0;
          #pragma unroll
          for (int dd = 0; dd < 16; ++dd){
            int Gv = 64 + dg*16 + dd;
            H8 vv; vv.v = rdq(qk, Gv, npair, wl);
            half2T p0 = pk2(av[0][dd]), p1 = pk2(av[1][dd]);
            po[0][0] += p0*vv.h2[0]; po[0][1] += p0*vv.h2[1];
            po[1][0] += p1*vv.h2[2]; po[1][1] += p1*vv.h2[3];
          }
          #pragma unroll
          for (int n2 = 0; n2 < 2; ++n2){
            po[n2][0] += h2shfl_xor(po[n2][0], 1);
            po[n2][1] += h2shfl_xor(po[n2][1], 1);
            float inv = __builtin_amdgcn_rcpf(sm[n2]);
            halfT ih = (halfT)inv;
            half2T iv = { ih, ih };
            // lane dg writes s-pair dg of its quad as one u32
            H2U wd; wd.h = po[n2][dg] * iv;
            int n   = npair*2 + n2;
            int slot = 1 + (ci >> 4);
            int ych  = (ci & 15) | (n << 4);
            int px0  = dg*32 + 2*wl;
            int u16i = slot*4096 + ych*64 + (px0 ^ ((ych & 7) << 3));
            *(uint32_t*)&bands[u16i] = wd.u;
          }
        }
      }
    }
    __syncthreads();
  }

  // ---------------- phase D: iDWT + coalesced store -----------------------
  for (int it = 0; it < 2; ++it){
    int s = it * 512 + tid;
    int ch = s >> 4, row = (s >> 2) & 3, seg = s & 3;
    int ych = (ch >> 2) | ((ch & 3) << 4);
    int px0 = (row >> 1)*32 + seg*8;
    int base = ych*64 + (px0 ^ ((ych & 7) << 3));
    H8 y0, y1, y2, y3;
    y0.v = *(const half8*)&bands[0*4096 + base];
    y1.v = *(const half8*)&bands[1*4096 + base];
    y2.v = *(const half8*)&bands[2*4096 + base];
    y3.v = *(const half8*)&bands[3*4096 + base];
    float o[16];
    #pragma unroll
    for (int p = 0; p < 8; ++p){
      float a0 = (float)y0.v[p];
      float a1 = (float)y1.v[p];
      float a2 = (float)y2.v[p];
      float a3 = (float)y3.v[p];
      float e0, e1;
      if (row & 1){ e0 = 0.5f*(a0 + a1 - a2 - a3); e1 = 0.5f*(a0 + a1 + a2 + a3); }
      else        { e0 = 0.5f*(a0 - a1 - a2 + a3); e1 = 0.5f*(a0 - a1 + a2 - a3); }
      o[2*p] = e0; o[2*p + 1] = e1;
    }
    float* dst = out + (((size_t)b*64 + ch)*256 + (size_t)(4*hw + row))*256 + col0 + seg*16;
    ((float4*)dst)[0] = make_float4(o[0],  o[1],  o[2],  o[3]);
    ((float4*)dst)[1] = make_float4(o[4],  o[5],  o[6],  o[7]);
    ((float4*)dst)[2] = make_float4(o[8],  o[9],  o[10], o[11]);
    ((float4*)dst)[3] = make_float4(o[12], o[13], o[14], o[15]);
  }
}

// ---------------------------------------------------------------------------
extern "C" void kernel_launch(void* const* d_in, const int* in_sizes, int n_in,
                              void* d_out, int out_size, void* d_ws, size_t ws_size,
                              hipStream_t stream){
  const float* x   = (const float*)d_in[0];
  const float* wlh = (const float*)d_in[1];
  const float* wm  = (const float*)d_in[2];
  float* out = (float*)d_out;
  halfT* wH = (halfT*)d_ws;                // 61440 f16 = 122880 B

  hipLaunchKernelGGL(k_wt,    dim3(240),  dim3(256), 0, stream, wlh, wm, wH);
  hipLaunchKernelGGL(k_fused, dim3(2048), dim3(512), 0, stream, x, wH, out);
}